// Round 11
// baseline (70.050 us; speedup 1.0000x reference)
//
#include <hip/hip_runtime.h>
#include <math.h>

#define NPTS   4096
#define BATCH  8
#define NBD    16                 // batch * 2 directions
#define BLOCK  512
#define PN     8                  // p points per thread (512*8 = 4096 = all n)
#define MCHUNK 128                // q points per block
#define NCHUNK 32                 // 4096 / 128
// grid = NBD * NCHUNK = 512 blocks = 2 blocks/CU = 16 waves/CU

// Single fused kernel. Each block: one (bd, m-chunk).
//  phase 1: partial mins of d2 = |p|^2 + (|q|^2 - 2 p.q) over its 128 q,
//           for all 4096 n (PN=8 scalar fmaf — the formulation whose slot
//           count matches its model), plain stores to part[bd][chunk][n].
//  phase 2: last arriver per bd (atomicAdd counter) reduces part[bd]
//           (min across 32 chunks per n, max over n) -> bdmax[bd].
//  phase 3: last of the 16 reducers combines dirs, sqrt, mean -> out.
// bd = b*2 + dir. dir 0: p=x, q=y; dir 1: p=y, q=x.
__global__ __launch_bounds__(BLOCK) void fused_kernel(
    const float* __restrict__ x, const float* __restrict__ y,
    float* __restrict__ part, float* __restrict__ bdmax,
    unsigned int* __restrict__ cnt, unsigned int* __restrict__ fin,
    float* __restrict__ out) {
  const int bd    = blockIdx.x >> 5;
  const int chunk = blockIdx.x & (NCHUNK - 1);
  const int b     = bd >> 1;
  const int dir   = bd & 1;

  const float* Pb = ((dir == 0) ? x : y) + (size_t)b * NPTS * 3;
  const float* Qb = ((dir == 0) ? y : x) + (size_t)b * NPTS * 3
                    + (size_t)chunk * MCHUNK * 3;

  __shared__ float4 qs[MCHUNK];  // (-2qx, -2qy, -2qz, |q|^2)
  if (threadIdx.x < MCHUNK) {
    const int m = threadIdx.x;
    const float gx = Qb[3 * m + 0], gy = Qb[3 * m + 1], gz = Qb[3 * m + 2];
    qs[m] = make_float4(-2.0f * gx, -2.0f * gy, -2.0f * gz,
                        gx * gx + gy * gy + gz * gz);
  }
  __syncthreads();

  float px[PN], py[PN], pz[PN], p2[PN], mn[PN];
#pragma unroll
  for (int i = 0; i < PN; ++i) {
    const int n = threadIdx.x + i * BLOCK;
    px[i] = Pb[3 * n + 0];
    py[i] = Pb[3 * n + 1];
    pz[i] = Pb[3 * n + 2];
    p2[i] = px[i] * px[i] + py[i] * py[i] + pz[i] * pz[i];
    mn[i] = 3.4e38f;
  }

#pragma unroll 2
  for (int g = 0; g < MCHUNK; g += 4) {
    const float4 q0 = qs[g + 0];  // uniform addr -> broadcast ds_read_b128
    const float4 q1 = qs[g + 1];
    const float4 q2 = qs[g + 2];
    const float4 q3 = qs[g + 3];
#pragma unroll
    for (int i = 0; i < PN; ++i) {
      const float t0 = fmaf(px[i], q0.x, fmaf(py[i], q0.y, fmaf(pz[i], q0.z, q0.w)));
      const float t1 = fmaf(px[i], q1.x, fmaf(py[i], q1.y, fmaf(pz[i], q1.z, q1.w)));
      const float t2 = fmaf(px[i], q2.x, fmaf(py[i], q2.y, fmaf(pz[i], q2.z, q2.w)));
      const float t3 = fmaf(px[i], q3.x, fmaf(py[i], q3.y, fmaf(pz[i], q3.z, q3.w)));
      mn[i] = fminf(fminf(t3, mn[i]), fminf(fminf(t0, t1), t2));
    }
  }

  float* wp = part + ((size_t)bd * NCHUNK + chunk) * NPTS + threadIdx.x;
#pragma unroll
  for (int i = 0; i < PN; ++i)
    wp[i * BLOCK] = mn[i] + p2[i];

  // ---- completion: last arriver of this bd becomes the reducer ----
  __syncthreads();           // all stores issued by all threads
  __shared__ unsigned int who;
  if (threadIdx.x == 0) {
    __threadfence();         // make part[] visible at device scope
    who = atomicAdd(&cnt[bd], 1u);
  }
  __syncthreads();
  if (who != NCHUNK - 1) return;

  // ---- phase 2: reduce part[bd]: min over 32 chunks per n, max over n ----
  __threadfence();           // acquire: see all writers' part[]
  const float4* base = (const float4*)(part + (size_t)bd * NCHUNK * NPTS);
  float mx = 0.0f;
#pragma unroll
  for (int r = 0; r < NPTS / 4 / BLOCK; ++r) {       // 2 iterations
    const int v = threadIdx.x + r * BLOCK;
    float4 mn4 = base[v];
#pragma unroll
    for (int c = 1; c < NCHUNK; ++c) {
      const float4 t = base[(size_t)c * (NPTS / 4) + v];
      mn4.x = fminf(mn4.x, t.x);
      mn4.y = fminf(mn4.y, t.y);
      mn4.z = fminf(mn4.z, t.z);
      mn4.w = fminf(mn4.w, t.w);
    }
    mx = fmaxf(mx, fmaxf(fmaxf(mn4.x, mn4.y), fmaxf(mn4.z, mn4.w)));
  }
  for (int off = 32; off > 0; off >>= 1)
    mx = fmaxf(mx, __shfl_down(mx, off));

  __shared__ float w[BLOCK / 64];
  if ((threadIdx.x & 63) == 0) w[threadIdx.x >> 6] = mx;
  __syncthreads();

  __shared__ unsigned int whof;
  if (threadIdx.x == 0) {
    float m = w[0];
#pragma unroll
    for (int i = 1; i < BLOCK / 64; ++i) m = fmaxf(m, w[i]);
    bdmax[bd] = m;
    __threadfence();
    whof = atomicAdd(fin, 1u);
  }
  __syncthreads();
  if (whof != NBD - 1) return;

  // ---- phase 3: final combine ----
  if (threadIdx.x == 0) {
    __threadfence();
    float s = 0.0f;
#pragma unroll
    for (int bb = 0; bb < BATCH; ++bb)
      s += sqrtf(fmaxf(fmaxf(bdmax[2 * bb], bdmax[2 * bb + 1]), 0.0f));
    out[0] = s / (float)BATCH;
  }
}

extern "C" void kernel_launch(void* const* d_in, const int* in_sizes, int n_in,
                              void* d_out, int out_size, void* d_ws, size_t ws_size,
                              hipStream_t stream) {
  const float* x = (const float*)d_in[0];
  const float* y = (const float*)d_in[1];
  float* part  = (float*)d_ws;                          // 16*32*4096 floats = 8 MB
  float* bdmax = part + (size_t)NBD * NCHUNK * NPTS;    // 16 floats
  unsigned int* cnt = (unsigned int*)(bdmax + NBD);     // 16 uints
  unsigned int* fin = cnt + NBD;                        // 1 uint
  float* out = (float*)d_out;

  hipMemsetAsync(cnt, 0, (NBD + 1) * sizeof(unsigned int), stream);
  fused_kernel<<<NBD * NCHUNK, BLOCK, 0, stream>>>(x, y, part, bdmax, cnt, fin, out);
}

// Round 12
// 35.676 us; speedup vs baseline: 1.9635x; 1.9635x over previous
//
#include <hip/hip_runtime.h>
#include <math.h>

#define NPTS   4096
#define BATCH  8
#define NBD    16                 // batch * 2 directions
#define BLOCK  256
#define PN     8                  // p points per thread
#define MCHUNK 256                // q points staged per block
#define NTILE  (BLOCK * PN)       // 2048 n per block
#define NBLK   (NPTS / NTILE)     // 2
#define NCHUNK (NPTS / MCHUNK)    // 16
// pass1 grid = (2, 16, 16) = 512 blocks = 2/CU, 8 waves/CU

// Pass 1: per (bd, m-chunk, n-tile), partial min over the chunk of
// t = |q|^2 - 2 p.q (q pre-transformed in LDS as one float4/point);
// store mn + |p|^2 to part. Block (0,0,0) also zeroes out[0] (safe: the
// reduce kernel is a separate, stream-ordered dispatch).
// bd = b*2 + dir. dir 0: p=x, q=y; dir 1: p=y, q=x.
__global__ __launch_bounds__(BLOCK) void partial_min_kernel(
    const float* __restrict__ x, const float* __restrict__ y,
    float* __restrict__ part, float* __restrict__ out) {
  if (blockIdx.x == 0 && blockIdx.y == 0 && blockIdx.z == 0 && threadIdx.x == 0)
    out[0] = 0.0f;

  const int bd  = blockIdx.z;
  const int b   = bd >> 1;
  const int dir = bd & 1;

  const float* Pb = ((dir == 0) ? x : y) + (size_t)b * NPTS * 3;
  const float* Qb = ((dir == 0) ? y : x) + (size_t)b * NPTS * 3
                    + (size_t)blockIdx.y * MCHUNK * 3;

  __shared__ float4 qs[MCHUNK];  // (-2qx, -2qy, -2qz, |q|^2)
  {
    const int m = threadIdx.x;   // MCHUNK == BLOCK
    const float gx = Qb[3 * m + 0], gy = Qb[3 * m + 1], gz = Qb[3 * m + 2];
    qs[m] = make_float4(-2.0f * gx, -2.0f * gy, -2.0f * gz,
                        gx * gx + gy * gy + gz * gz);
  }
  __syncthreads();

  const int n0 = blockIdx.x * NTILE + threadIdx.x;
  float px[PN], py[PN], pz[PN], p2[PN], mn[PN];
#pragma unroll
  for (int i = 0; i < PN; ++i) {
    const int n = n0 + i * BLOCK;
    px[i] = Pb[3 * n + 0];
    py[i] = Pb[3 * n + 1];
    pz[i] = Pb[3 * n + 2];
    p2[i] = px[i] * px[i] + py[i] * py[i] + pz[i] * pz[i];
    mn[i] = 3.4e38f;
  }

#pragma unroll 2
  for (int g = 0; g < MCHUNK; g += 4) {
    const float4 q0 = qs[g + 0];  // uniform addr -> broadcast ds_read_b128
    const float4 q1 = qs[g + 1];
    const float4 q2 = qs[g + 2];
    const float4 q3 = qs[g + 3];
#pragma unroll
    for (int i = 0; i < PN; ++i) {
      const float t0 = fmaf(px[i], q0.x, fmaf(py[i], q0.y, fmaf(pz[i], q0.z, q0.w)));
      const float t1 = fmaf(px[i], q1.x, fmaf(py[i], q1.y, fmaf(pz[i], q1.z, q1.w)));
      const float t2 = fmaf(px[i], q2.x, fmaf(py[i], q2.y, fmaf(pz[i], q2.z, q2.w)));
      const float t3 = fmaf(px[i], q3.x, fmaf(py[i], q3.y, fmaf(pz[i], q3.z, q3.w)));
      mn[i] = fminf(fminf(t3, mn[i]), fminf(fminf(t0, t1), t2));  // min3 pair
    }
  }

  float* wp = part + ((size_t)bd * NCHUNK + blockIdx.y) * NPTS + n0;
#pragma unroll
  for (int i = 0; i < PN; ++i)
    wp[i * BLOCK] = mn[i] + p2[i];
}

// Pass 2 (single dispatch): 8 blocks, one per batch; 1024 threads.
// For each direction: thread t owns float4 column t (4096 floats = 1024
// float4 -> exact cover, no loop); min across 16 chunks, max over lanes,
// wave+LDS max reduce. Then sqrt(max(dir0,dir1)) and atomicAdd into out.
__global__ __launch_bounds__(1024) void reduce_kernel(
    const float* __restrict__ part, float* __restrict__ out) {
  const int b = blockIdx.x;
  __shared__ float w[16];
  float m[2];

#pragma unroll
  for (int d = 0; d < 2; ++d) {
    const int bd = 2 * b + d;
    const float4* base = (const float4*)(part + (size_t)bd * NCHUNK * NPTS);
    const int v = threadIdx.x;

    float4 mn4 = base[v];
#pragma unroll
    for (int c = 1; c < NCHUNK; ++c) {
      const float4 t = base[(size_t)c * (NPTS / 4) + v];
      mn4.x = fminf(mn4.x, t.x);
      mn4.y = fminf(mn4.y, t.y);
      mn4.z = fminf(mn4.z, t.z);
      mn4.w = fminf(mn4.w, t.w);
    }
    float mx = fmaxf(fmaxf(mn4.x, mn4.y), fmaxf(mn4.z, mn4.w));
    for (int off = 32; off > 0; off >>= 1)
      mx = fmaxf(mx, __shfl_down(mx, off));
    if ((threadIdx.x & 63) == 0) w[threadIdx.x >> 6] = mx;
    __syncthreads();
    if (threadIdx.x == 0) {
      float mm = w[0];
#pragma unroll
      for (int i = 1; i < 16; ++i) mm = fmaxf(mm, w[i]);
      m[d] = mm;
    }
    __syncthreads();
  }

  if (threadIdx.x == 0)
    atomicAdd(out, sqrtf(fmaxf(fmaxf(m[0], m[1]), 0.0f)) * (1.0f / BATCH));
}

extern "C" void kernel_launch(void* const* d_in, const int* in_sizes, int n_in,
                              void* d_out, int out_size, void* d_ws, size_t ws_size,
                              hipStream_t stream) {
  const float* x = (const float*)d_in[0];
  const float* y = (const float*)d_in[1];
  float* part = (float*)d_ws;     // NBD*NCHUNK*NPTS floats = 4 MB
  float* out  = (float*)d_out;

  dim3 grid(NBLK, NCHUNK, NBD);   // (2, 16, 16) = 512 blocks
  partial_min_kernel<<<grid, BLOCK, 0, stream>>>(x, y, part, out);
  reduce_kernel<<<BATCH, 1024, 0, stream>>>(part, out);
}